// Round 6
// baseline (604.706 us; speedup 1.0000x reference)
//
#include <hip/hip_runtime.h>
#include <math.h>

#define B_ 8
#define S_ 2048
#define D_ 512
#define HSZ (B_ * S_ * D_)   // 8,388,608 elements

typedef _Float16 half8 __attribute__((ext_vector_type(8)));
typedef _Float16 half4h __attribute__((ext_vector_type(4)));
typedef float f32x4 __attribute__((ext_vector_type(4)));

constexpr float INV_SCALE = 0.044194173824159216f; // 1/sqrt(512)

// ================= cvt_all: fp16 convert + tiled transposes =================
__global__ __launch_bounds__(256) void cvt_all(const float* __restrict__ x,
                                               const float* __restrict__ W,
                                               _Float16* __restrict__ xh,
                                               _Float16* __restrict__ xhT,
                                               _Float16* __restrict__ WhT) {
    __shared__ float T[64 * 65];
    const int tid = threadIdx.x;
    const int blk = blockIdx.x;

    const float* src;
    _Float16* dstT;
    _Float16* dstL;
    int t0, d0, dstTld;
    if (blk < 2048) {
        int b = blk >> 8;
        int r = blk & 255;
        t0 = (r >> 3) * 64; d0 = (r & 7) * 64;
        src = x + (size_t)b * (S_ * D_);
        dstT = xhT + (size_t)b * (S_ * D_); dstTld = S_;
        dstL = xh + (size_t)b * (S_ * D_);
    } else {
        int r = blk - 2048;
        t0 = (r >> 3) * 64; d0 = (r & 7) * 64;
        src = W; dstT = WhT; dstTld = 512; dstL = nullptr;
    }

#pragma unroll
    for (int it = 0; it < 4; ++it) {
        int flat = it * 256 + tid;
        int row = flat >> 4, c4 = (flat & 15) * 4;
        float4 v = *(const float4*)(src + (size_t)(t0 + row) * 512 + d0 + c4);
        T[row * 65 + c4 + 0] = v.x; T[row * 65 + c4 + 1] = v.y;
        T[row * 65 + c4 + 2] = v.z; T[row * 65 + c4 + 3] = v.w;
        if (dstL) {
            half4h h = { (_Float16)v.x, (_Float16)v.y, (_Float16)v.z, (_Float16)v.w };
            *(half4h*)(dstL + (size_t)(t0 + row) * 512 + d0 + c4) = h;
        }
    }
    __syncthreads();
#pragma unroll
    for (int it = 0; it < 2; ++it) {
        int flat = it * 256 + tid;
        int d = flat >> 3, c = (flat & 7) * 8;
        half8 hv;
#pragma unroll
        for (int j = 0; j < 8; ++j) hv[j] = (_Float16)T[(c + j) * 65 + d];
        *(half8*)(dstT + (size_t)(d0 + d) * dstTld + t0 + c) = hv;
    }
}

// ================= MFMA GEMM: qwh = fp16( (xh @ W) * inv_scale ) =============
__global__ __launch_bounds__(256) void gemm_h(const _Float16* __restrict__ xh,
                                              const _Float16* __restrict__ WhT,
                                              _Float16* __restrict__ qwh) {
    const int tid = threadIdx.x;
    const int w = tid >> 6, lane = tid & 63, quad = lane >> 4, l16 = lane & 15;
    const int n0 = (blockIdx.x & 3) * 128 + w * 32;
    const int m0 = (blockIdx.x >> 2) * 128;

    f32x4 acc[8][2];
#pragma unroll
    for (int mt = 0; mt < 8; ++mt)
#pragma unroll
        for (int nt = 0; nt < 2; ++nt) acc[mt][nt] = (f32x4){0.f, 0.f, 0.f, 0.f};

#pragma unroll 2
    for (int kc = 0; kc < 16; ++kc) {
        half8 Bf[2];
#pragma unroll
        for (int nt = 0; nt < 2; ++nt)
            Bf[nt] = *(const half8*)(WhT + (size_t)(n0 + nt * 16 + l16) * 512 + kc * 32 + quad * 8);
#pragma unroll
        for (int mt = 0; mt < 8; ++mt) {
            half8 Af = *(const half8*)(xh + (size_t)(m0 + mt * 16 + l16) * 512 + kc * 32 + quad * 8);
            acc[mt][0] = __builtin_amdgcn_mfma_f32_16x16x32_f16(Af, Bf[0], acc[mt][0], 0, 0, 0);
            acc[mt][1] = __builtin_amdgcn_mfma_f32_16x16x32_f16(Af, Bf[1], acc[mt][1], 0, 0, 0);
        }
    }
#pragma unroll
    for (int mt = 0; mt < 8; ++mt)
#pragma unroll
        for (int nt = 0; nt < 2; ++nt)
#pragma unroll
            for (int r = 0; r < 4; ++r)
                qwh[(size_t)(m0 + mt * 16 + quad * 4 + r) * 512 + n0 + nt * 16 + l16] =
                    (_Float16)(acc[mt][nt][r] * INV_SCALE);
}

// ================= flash4: wave-independent MFMA flash attention ============
// Each WAVE owns 16 q-rows, sweeps all 2048 t's. Q in 64 VGPRs (B-frags),
// O in 128 VGPRs (32 f32x4 d-chunks). t-tile = 32. No inter-wave coupling:
// softmax is pure in-wave shuffles; P goes through 1.1 KB private LDS
// (within-wave lgkmcnt only). Sparse re-sync every 4 tiles keeps the 4
// waves' identical K/V streams L1-hot.
#define PSTR 36   // P row stride (halves): 18 dwords -> conflict-free-ish

__global__ __launch_bounds__(256, 1)
void flash4(const _Float16* __restrict__ xh, const _Float16* __restrict__ xhT,
            const _Float16* __restrict__ qwh, float* __restrict__ out) {
    __shared__ _Float16 Ps[4 * 16 * PSTR];

    const int tid = threadIdx.x;
    const int w = tid >> 6, lane = tid & 63, quad = lane >> 4, l16 = lane & 15;
    const int bx = blockIdx.x;
    const int b = bx & 7;                     // XCD swizzle: one batch per XCD
    const int q0 = ((bx >> 3) * 4 + w) * 16;  // this wave's 16 q-rows
    const size_t xb = (size_t)b * (S_ * D_);

    // Q B-frags in registers: Qr[kc][j] = qw[q0+l16][kc*32 + quad*8 + j]
    half8 Qr[16];
#pragma unroll
    for (int kc = 0; kc < 16; ++kc)
        Qr[kc] = *(const half8*)(qwh + xb + (size_t)(q0 + l16) * 512 + kc * 32 + quad * 8);

    f32x4 O[32];
#pragma unroll
    for (int dc = 0; dc < 32; ++dc) O[dc] = (f32x4){0.f, 0.f, 0.f, 0.f};
    float m = -1e30f, l = 0.f;

    _Float16* Pw = &Ps[w * 16 * PSTR];
    const _Float16* kb0 = xh + xb + (size_t)l16 * 512 + quad * 8;
    const _Float16* vb0 = xhT + xb + (size_t)l16 * S_ + quad * 8;

    for (int ti = 0; ti < S_ / 32; ++ti) {
        const int t0 = ti * 32;
        // ---- QK^T: S^T[t][q] for t-subtiles (t0..t0+15, +16..+31) ----
        f32x4 sA = {0.f, 0.f, 0.f, 0.f}, sB = {0.f, 0.f, 0.f, 0.f};
        const _Float16* ka = kb0 + (size_t)t0 * 512;
#pragma unroll
        for (int kc = 0; kc < 16; ++kc) {
            half8 KA = *(const half8*)(ka + kc * 32);
            half8 KB = *(const half8*)(ka + 16 * 512 + kc * 32);
            sA = __builtin_amdgcn_mfma_f32_16x16x32_f16(KA, Qr[kc], sA, 0, 0, 0);
            sB = __builtin_amdgcn_mfma_f32_16x16x32_f16(KB, Qr[kc], sB, 0, 0, 0);
        }
        // ---- in-wave softmax for q = l16 over the 32 t's ----
        float M = fmaxf(fmaxf(fmaxf(sA[0], sA[1]), fmaxf(sA[2], sA[3])),
                        fmaxf(fmaxf(sB[0], sB[1]), fmaxf(sB[2], sB[3])));
        M = fmaxf(M, __shfl_xor(M, 16));
        M = fmaxf(M, __shfl_xor(M, 32));
        float mn = fmaxf(m, M);
        float a = __expf(m - mn);
        float pA[4], pB[4];
#pragma unroll
        for (int r = 0; r < 4; ++r) { pA[r] = __expf(sA[r] - mn); pB[r] = __expf(sB[r] - mn); }
        float R = pA[0] + pA[1] + pA[2] + pA[3] + pB[0] + pB[1] + pB[2] + pB[3];
        R += __shfl_xor(R, 16);
        R += __shfl_xor(R, 32);
        l = a * l + R;
        m = mn;
        // ---- P[q][t] to private LDS (within-wave round-trip) ----
        half4h hA = { (_Float16)pA[0], (_Float16)pA[1], (_Float16)pA[2], (_Float16)pA[3] };
        half4h hB = { (_Float16)pB[0], (_Float16)pB[1], (_Float16)pB[2], (_Float16)pB[3] };
        *(half4h*)&Pw[l16 * PSTR + quad * 4] = hA;
        *(half4h*)&Pw[l16 * PSTR + 16 + quad * 4] = hB;
        // ---- rescale O when any of this wave's 16 maxes moved ----
        if (__any(a < 1.f)) {
            float ar[4];
#pragma unroll
            for (int r = 0; r < 4; ++r) ar[r] = __shfl(a, quad * 4 + r);
#pragma unroll
            for (int dc = 0; dc < 32; ++dc)
#pragma unroll
                for (int r = 0; r < 4; ++r) O[dc][r] *= ar[r];
        }
        // ---- PV: O[q][d] += P·V over 32 d-chunks (K=32) ----
        half8 Af = *(const half8*)&Pw[l16 * PSTR + quad * 8];
        const _Float16* vb = vb0 + t0;
#pragma unroll
        for (int dc = 0; dc < 32; ++dc) {
            half8 Vf = *(const half8*)(vb + (size_t)(dc * 16) * S_);
            O[dc] = __builtin_amdgcn_mfma_f32_16x16x32_f16(Af, Vf, O[dc], 0, 0, 0);
        }
        // sparse re-sync: keep the 4 waves' shared K/V streams L1-resident
        if ((ti & 3) == 3) __syncthreads();
    }
    // ---- epilogue: out = O / l ----
    float inv[4];
#pragma unroll
    for (int r = 0; r < 4; ++r) inv[r] = 1.0f / __shfl(l, quad * 4 + r);
#pragma unroll
    for (int dc = 0; dc < 32; ++dc)
#pragma unroll
        for (int r = 0; r < 4; ++r)
            out[xb + (size_t)(q0 + quad * 4 + r) * 512 + dc * 16 + l16] = O[dc][r] * inv[r];
}

// ================= fp32 fallback (round 1) ==================================
__global__ __launch_bounds__(256) void xw_gemm_f32(const float* __restrict__ A,
                                                   const float* __restrict__ W,
                                                   float* __restrict__ C) {
    __shared__ float As[16][65];
    __shared__ float Bs[16][64];
    const int tid = threadIdx.x;
    const int row0 = blockIdx.y * 64, col0 = blockIdx.x * 64;
    const int ty = tid / 16, tx = tid % 16;
    float acc[4][4] = {};
    const int ar = tid / 4, ak = (tid % 4) * 4, bk = tid / 16, bn = (tid % 16) * 4;
    for (int k0 = 0; k0 < 512; k0 += 16) {
        float4 a4 = *(const float4*)(A + (size_t)(row0 + ar) * 512 + k0 + ak);
        float4 b4 = *(const float4*)(W + (size_t)(k0 + bk) * 512 + col0 + bn);
        __syncthreads();
        As[ak + 0][ar] = a4.x; As[ak + 1][ar] = a4.y;
        As[ak + 2][ar] = a4.z; As[ak + 3][ar] = a4.w;
        *(float4*)&Bs[bk][bn] = b4;
        __syncthreads();
#pragma unroll
        for (int kk = 0; kk < 16; kk++) {
            float a[4], b[4];
#pragma unroll
            for (int i = 0; i < 4; i++) a[i] = As[kk][ty * 4 + i];
#pragma unroll
            for (int j = 0; j < 4; j++) b[j] = Bs[kk][tx * 4 + j];
#pragma unroll
            for (int i = 0; i < 4; i++)
#pragma unroll
                for (int j = 0; j < 4; j++) acc[i][j] += a[i] * b[j];
        }
    }
#pragma unroll
    for (int i = 0; i < 4; i++) {
        float4 o = make_float4(acc[i][0] * INV_SCALE, acc[i][1] * INV_SCALE,
                               acc[i][2] * INV_SCALE, acc[i][3] * INV_SCALE);
        *(float4*)(C + (size_t)(row0 + ty * 4 + i) * 512 + col0 + tx * 4) = o;
    }
}

__global__ __launch_bounds__(256) void flash_f32(const float* __restrict__ x,
                                                 const float* __restrict__ qw,
                                                 float* __restrict__ out) {
    __shared__ float4 kt[16 * 136];
    const int tid = threadIdx.x;
    const int q = tid >> 3, g = tid & 7;
    const int blk = blockIdx.x;
    const int b = blk >> 6;
    const int qrow = (blk & 63) * 32 + q;
    const size_t xbase = (size_t)b * S_ * D_;
    float qwr[64];
    {
        const float4* p = (const float4*)(qw + xbase + (size_t)qrow * D_ + g * 64);
#pragma unroll
        for (int i4 = 0; i4 < 16; i4++) {
            float4 v = p[i4];
            qwr[4 * i4 + 0] = v.x; qwr[4 * i4 + 1] = v.y;
            qwr[4 * i4 + 2] = v.z; qwr[4 * i4 + 3] = v.w;
        }
    }
    float oa[64];
#pragma unroll
    for (int i = 0; i < 64; i++) oa[i] = 0.f;
    float m = -1e30f, l = 0.f;
    const float4* x4 = (const float4*)(x + xbase);
    for (int t0 = 0; t0 < S_; t0 += 16) {
        __syncthreads();
#pragma unroll
        for (int j = 0; j < 8; j++) {
            int f = tid + j * 256;
            int tt = f >> 7, c = f & 127;
            kt[tt * 136 + (c >> 4) * 17 + (c & 15)] = x4[(size_t)(t0 + tt) * 128 + c];
        }
        __syncthreads();
#pragma unroll 1
        for (int tt = 0; tt < 16; tt++) {
            float4 kv[16];
            const float4* kp = &kt[tt * 136 + g * 17];
#pragma unroll
            for (int i4 = 0; i4 < 16; i4++) kv[i4] = kp[i4];
            float s = 0.f;
#pragma unroll
            for (int i4 = 0; i4 < 16; i4++)
                s += qwr[4 * i4] * kv[i4].x + qwr[4 * i4 + 1] * kv[i4].y
                   + qwr[4 * i4 + 2] * kv[i4].z + qwr[4 * i4 + 3] * kv[i4].w;
            s += __shfl_xor(s, 1, 64); s += __shfl_xor(s, 2, 64); s += __shfl_xor(s, 4, 64);
            if (s > m) {
                float alpha = __expf(m - s);
                l *= alpha;
#pragma unroll
                for (int i = 0; i < 64; i++) oa[i] *= alpha;
                m = s;
            }
            float p = __expf(s - m);
            l += p;
#pragma unroll
            for (int i4 = 0; i4 < 16; i4++) {
                oa[4 * i4 + 0] += p * kv[i4].x; oa[4 * i4 + 1] += p * kv[i4].y;
                oa[4 * i4 + 2] += p * kv[i4].z; oa[4 * i4 + 3] += p * kv[i4].w;
            }
        }
    }
    float inv_l = 1.0f / l;
    float4* op = (float4*)(out + xbase + (size_t)qrow * D_ + g * 64);
#pragma unroll
    for (int i4 = 0; i4 < 16; i4++)
        op[i4] = make_float4(oa[4 * i4] * inv_l, oa[4 * i4 + 1] * inv_l,
                             oa[4 * i4 + 2] * inv_l, oa[4 * i4 + 3] * inv_l);
}

// ================= launch ====================================================
extern "C" void kernel_launch(void* const* d_in, const int* in_sizes, int n_in,
                              void* d_out, int out_size, void* d_ws, size_t ws_size,
                              hipStream_t stream) {
    const float* x = (const float*)d_in[0];
    const float* W = (const float*)d_in[1];
    float* out = (float*)d_out;

    const size_t F16 = (size_t)HSZ * sizeof(_Float16);     // 16,777,216
    const size_t off_qwh = 0;
    const size_t off_xh  = F16;
    const size_t off_xhT = 2 * F16;
    const size_t off_WhT = 3 * F16;
    const size_t base    = 3 * F16 + 512 * 512 * sizeof(_Float16);   // 50,855,936

    if (ws_size >= base) {
        _Float16* qwh = (_Float16*)((char*)d_ws + off_qwh);
        _Float16* xh  = (_Float16*)((char*)d_ws + off_xh);
        _Float16* xhT = (_Float16*)((char*)d_ws + off_xhT);
        _Float16* WhT = (_Float16*)((char*)d_ws + off_WhT);

        cvt_all<<<2112, 256, 0, stream>>>(x, W, xh, xhT, WhT);
        gemm_h<<<512, 256, 0, stream>>>(xh, WhT, qwh);
        flash4<<<256, 256, 0, stream>>>(xh, xhT, qwh, out);
    } else {
        const size_t needf = (size_t)HSZ * sizeof(float);
        float* xw = (ws_size >= needf) ? (float*)d_ws : out;
        dim3 g1(512 / 64, (B_ * S_) / 64);
        xw_gemm_f32<<<g1, 256, 0, stream>>>(x, W, xw);
        flash_f32<<<B_ * (S_ / 32), 256, 0, stream>>>(x, xw, out);
    }
}

// Round 7
// 282.943 us; speedup vs baseline: 2.1372x; 2.1372x over previous
//
#include <hip/hip_runtime.h>
#include <math.h>

#define B_ 8
#define S_ 2048
#define D_ 512
#define HSZ (B_ * S_ * D_)   // 8,388,608 elements

typedef _Float16 half8 __attribute__((ext_vector_type(8)));
typedef _Float16 half4h __attribute__((ext_vector_type(4)));
typedef float f32x4 __attribute__((ext_vector_type(4)));

constexpr float INV_SCALE = 0.044194173824159216f; // 1/sqrt(512)

// async global->LDS DMA, 16 B per lane, lane i lands at ldsbase + i*16
__device__ __forceinline__ void gld_lds16(const _Float16* g, _Float16* l) {
    __builtin_amdgcn_global_load_lds(
        (const __attribute__((address_space(1))) unsigned int*)g,
        (__attribute__((address_space(3))) unsigned int*)l, 16, 0, 0);
}

// ================= cvt_all: fp16 convert + tiled transposes =================
__global__ __launch_bounds__(256) void cvt_all(const float* __restrict__ x,
                                               const float* __restrict__ W,
                                               _Float16* __restrict__ xh,
                                               _Float16* __restrict__ xhT,
                                               _Float16* __restrict__ WhT) {
    __shared__ float T[64 * 65];
    const int tid = threadIdx.x;
    const int blk = blockIdx.x;

    const float* src;
    _Float16* dstT;
    _Float16* dstL;
    int t0, d0, dstTld;
    if (blk < 2048) {
        int b = blk >> 8;
        int r = blk & 255;
        t0 = (r >> 3) * 64; d0 = (r & 7) * 64;
        src = x + (size_t)b * (S_ * D_);
        dstT = xhT + (size_t)b * (S_ * D_); dstTld = S_;
        dstL = xh + (size_t)b * (S_ * D_);
    } else {
        int r = blk - 2048;
        t0 = (r >> 3) * 64; d0 = (r & 7) * 64;
        src = W; dstT = WhT; dstTld = 512; dstL = nullptr;
    }

#pragma unroll
    for (int it = 0; it < 4; ++it) {
        int flat = it * 256 + tid;
        int row = flat >> 4, c4 = (flat & 15) * 4;
        float4 v = *(const float4*)(src + (size_t)(t0 + row) * 512 + d0 + c4);
        T[row * 65 + c4 + 0] = v.x; T[row * 65 + c4 + 1] = v.y;
        T[row * 65 + c4 + 2] = v.z; T[row * 65 + c4 + 3] = v.w;
        if (dstL) {
            half4h h = { (_Float16)v.x, (_Float16)v.y, (_Float16)v.z, (_Float16)v.w };
            *(half4h*)(dstL + (size_t)(t0 + row) * 512 + d0 + c4) = h;
        }
    }
    __syncthreads();
#pragma unroll
    for (int it = 0; it < 2; ++it) {
        int flat = it * 256 + tid;
        int d = flat >> 3, c = (flat & 7) * 8;
        half8 hv;
#pragma unroll
        for (int j = 0; j < 8; ++j) hv[j] = (_Float16)T[(c + j) * 65 + d];
        *(half8*)(dstT + (size_t)(d0 + d) * dstTld + t0 + c) = hv;
    }
}

// ================= MFMA GEMM: qwh = fp16( (xh @ W) * inv_scale ) =============
// 128x128 block tile, 4 waves each 128m x 32n. W fragments RESIDENT in
// registers (128 VGPR); A fragments batch-loaded 8 at a time.
__global__ __launch_bounds__(256, 2) void gemm_h(const _Float16* __restrict__ xh,
                                                 const _Float16* __restrict__ WhT,
                                                 _Float16* __restrict__ qwh) {
    const int tid = threadIdx.x;
    const int w = tid >> 6, lane = tid & 63, quad = lane >> 4, l16 = lane & 15;
    const int n0 = (blockIdx.x & 3) * 128 + w * 32;
    const int m0 = (blockIdx.x >> 2) * 128;

    half8 Bf[16][2];
#pragma unroll
    for (int kc = 0; kc < 16; ++kc)
#pragma unroll
        for (int nt = 0; nt < 2; ++nt)
            Bf[kc][nt] = *(const half8*)(WhT + (size_t)(n0 + nt * 16 + l16) * 512 + kc * 32 + quad * 8);

    f32x4 acc[8][2];
#pragma unroll
    for (int mt = 0; mt < 8; ++mt)
#pragma unroll
        for (int nt = 0; nt < 2; ++nt) acc[mt][nt] = (f32x4){0.f, 0.f, 0.f, 0.f};

#pragma unroll
    for (int mt = 0; mt < 8; ++mt) {
        const _Float16* arow = xh + (size_t)(m0 + mt * 16 + l16) * 512 + quad * 8;
#pragma unroll
        for (int h = 0; h < 2; ++h) {
            half8 Af[8];
#pragma unroll
            for (int k8 = 0; k8 < 8; ++k8)
                Af[k8] = *(const half8*)(arow + (h * 8 + k8) * 32);
#pragma unroll
            for (int k8 = 0; k8 < 8; ++k8) {
                acc[mt][0] = __builtin_amdgcn_mfma_f32_16x16x32_f16(Af[k8], Bf[h * 8 + k8][0], acc[mt][0], 0, 0, 0);
                acc[mt][1] = __builtin_amdgcn_mfma_f32_16x16x32_f16(Af[k8], Bf[h * 8 + k8][1], acc[mt][1], 0, 0, 0);
            }
        }
    }
#pragma unroll
    for (int mt = 0; mt < 8; ++mt)
#pragma unroll
        for (int nt = 0; nt < 2; ++nt)
#pragma unroll
            for (int r = 0; r < 4; ++r)
                qwh[(size_t)(m0 + mt * 16 + quad * 4 + r) * 512 + n0 + nt * 16 + l16] =
                    (_Float16)(acc[mt][nt][r] * INV_SCALE);
}

// ================= flash5: DMA-staged MFMA flash attention ==================
// TQ=32 q/block (512 blocks = 2/CU), TK=32, 4 waves.
// Wave (th = w&1, qs = w>>1) computes S^T quadrant [16t x 16q].
// K tile double-buffered in LDS via global_load_lds; DMA for tile i+1 issued
// mid-tile i, drained for free at the single per-tile barrier.
// Q in registers (per-wave q-sub, 64 VGPR). V B-frags batch-loaded from
// global pre-barrier (8 frags/wave). PV: wave owns d-cols [w*128, +128).
#define KROW 520   // 512 + 8 pad halves
#define PSTR 72    // 32 t + 40 pad? (keeps flash2's validated bank pattern)

__global__ __launch_bounds__(256, 2)
void flash5(const _Float16* __restrict__ xh, const _Float16* __restrict__ xhT,
            const _Float16* __restrict__ qwh, float* __restrict__ out) {
    __shared__ _Float16 Kbuf[2][32 * KROW];   // 2 x 33,280 B
    __shared__ _Float16 Ps[2][16 * PSTR];     // per q-sub: 16 q rows x 32 t
    __shared__ float smM[2][16][2];
    __shared__ float smR[2][16][2];

    const int tid = threadIdx.x;
    const int w = tid >> 6, lane = tid & 63, quad = lane >> 4, l16 = lane & 15;
    const int th = w & 1, qs = w >> 1;
    const int bx = blockIdx.x;
    const int b = bx & 7;                 // XCD swizzle: one batch per XCD
    const int q0 = (bx >> 3) * 32;
    const size_t xb = (size_t)b * (S_ * D_);

    // Q B-frags for this wave's q-sub (16 q), in registers.
    half8 Qr[16];
#pragma unroll
    for (int kc = 0; kc < 16; ++kc)
        Qr[kc] = *(const half8*)(qwh + xb + (size_t)(q0 + qs * 16 + l16) * 512 + kc * 32 + quad * 8);

    // Prologue: DMA tile 0 into Kbuf[0]. Each wave stages rows w*8..w*8+8.
#pragma unroll
    for (int r = 0; r < 8; ++r) {
        int row = w * 8 + r;
        gld_lds16(xh + xb + (size_t)row * 512 + lane * 8, &Kbuf[0][row * KROW]);
    }
    __syncthreads();

    f32x4 O[2][8];
#pragma unroll
    for (int q2 = 0; q2 < 2; ++q2)
#pragma unroll
        for (int dc = 0; dc < 8; ++dc) O[q2][dc] = (f32x4){0.f, 0.f, 0.f, 0.f};
    float m0 = -1e30f, m1 = -1e30f, l0 = 0.f, l1 = 0.f;

    const _Float16* vROW = xhT + xb + (size_t)(w * 128 + l16) * S_ + quad * 8;

    const int ntiles = S_ / 32;  // 64
    for (int ti = 0; ti < ntiles; ++ti) {
        const int t0 = ti * 32;
        const int cur = ti & 1, nxt = cur ^ 1;
        // ---- QK^T quadrant: S^T[t = th*16.., q = qs*16..] ----
        f32x4 s = {0.f, 0.f, 0.f, 0.f};
        const _Float16* kb = &Kbuf[cur][(th * 16 + l16) * KROW + quad * 8];
#pragma unroll
        for (int kc = 0; kc < 16; ++kc) {
            half8 Af = *(const half8*)(kb + kc * 32);
            s = __builtin_amdgcn_mfma_f32_16x16x32_f16(Af, Qr[kc], s, 0, 0, 0);
        }
        // ---- issue DMA for next K tile (drained at the barrier below) ----
        {
            const int t1 = (ti + 1 < ntiles) ? t0 + 32 : 0;   // wrap: harmless
#pragma unroll
            for (int r = 0; r < 8; ++r) {
                int row = w * 8 + r;
                gld_lds16(xh + xb + (size_t)(t1 + row) * 512 + lane * 8,
                          &Kbuf[nxt][row * KROW]);
            }
        }
        // ---- batch-issue this tile's V fragments (global, L2-resident) ----
        half8 Vf[8];
        {
            const _Float16* vb = vROW + t0;
#pragma unroll
            for (int dc = 0; dc < 8; ++dc)
                Vf[dc] = *(const half8*)(vb + (size_t)(dc * 16) * S_);
        }
        // ---- wave-local softmax over this quadrant's 16 t (per q=l16) ----
        float M = fmaxf(fmaxf(s[0], s[1]), fmaxf(s[2], s[3]));
        M = fmaxf(M, __shfl_xor(M, 16));
        M = fmaxf(M, __shfl_xor(M, 32));
        float p[4];
#pragma unroll
        for (int r = 0; r < 4; ++r) p[r] = __expf(s[r] - M);
        float R = p[0] + p[1] + p[2] + p[3];
        R += __shfl_xor(R, 16);
        R += __shfl_xor(R, 32);
        if (lane < 16) { smM[qs][l16][th] = M; smR[qs][l16][th] = R; }
        half4h hp = { (_Float16)p[0], (_Float16)p[1], (_Float16)p[2], (_Float16)p[3] };
        *(half4h*)&Ps[qs][l16 * PSTR + th * 16 + quad * 4] = hp;
        __syncthreads();   // the ONLY barrier: P/stats visible, DMA+Vf drained
        // ---- merge pairwise stats (both q-subs, every wave) ----
        float M00 = smM[0][l16][0], M01 = smM[0][l16][1];
        float M10 = smM[1][l16][0], M11 = smM[1][l16][1];
        float R00 = smR[0][l16][0], R01 = smR[0][l16][1];
        float R10 = smR[1][l16][0], R11 = smR[1][l16][1];
        float mn0 = fmaxf(m0, fmaxf(M00, M01));
        float mn1 = fmaxf(m1, fmaxf(M10, M11));
        float a0 = __expf(m0 - mn0), a1 = __expf(m1 - mn1);
        float c00 = __expf(M00 - mn0), c01 = __expf(M01 - mn0);
        float c10 = __expf(M10 - mn1), c11 = __expf(M11 - mn1);
        l0 = a0 * l0 + R00 * c00 + R01 * c01;
        l1 = a1 * l1 + R10 * c10 + R11 * c11;
        m0 = mn0; m1 = mn1;
        // ---- rescale O when any max moved ----
        if (__any((a0 < 1.f) || (a1 < 1.f))) {
            float ar0[4], ar1[4];
#pragma unroll
            for (int r = 0; r < 4; ++r) {
                ar0[r] = __shfl(a0, quad * 4 + r);
                ar1[r] = __shfl(a1, quad * 4 + r);
            }
#pragma unroll
            for (int dc = 0; dc < 8; ++dc)
#pragma unroll
                for (int r = 0; r < 4; ++r) { O[0][dc][r] *= ar0[r]; O[1][dc][r] *= ar1[r]; }
        }
        // ---- P A-frags (t-half correction per quad-pair), then PV ----
        half8 A0 = *(const half8*)&Ps[0][l16 * PSTR + quad * 8];
        half8 A1 = *(const half8*)&Ps[1][l16 * PSTR + quad * 8];
        _Float16 sc0 = (_Float16)((quad < 2) ? c00 : c01);
        _Float16 sc1 = (_Float16)((quad < 2) ? c10 : c11);
#pragma unroll
        for (int j = 0; j < 8; ++j) { A0[j] *= sc0; A1[j] *= sc1; }
#pragma unroll
        for (int dc = 0; dc < 8; ++dc) {
            O[0][dc] = __builtin_amdgcn_mfma_f32_16x16x32_f16(A0, Vf[dc], O[0][dc], 0, 0, 0);
            O[1][dc] = __builtin_amdgcn_mfma_f32_16x16x32_f16(A1, Vf[dc], O[1][dc], 0, 0, 0);
        }
    }
    // ---- epilogue: out = O / l ----
    float inv0[4], inv1[4];
#pragma unroll
    for (int r = 0; r < 4; ++r) {
        inv0[r] = 1.0f / __shfl(l0, quad * 4 + r);
        inv1[r] = 1.0f / __shfl(l1, quad * 4 + r);
    }
#pragma unroll
    for (int q2 = 0; q2 < 2; ++q2)
#pragma unroll
        for (int dc = 0; dc < 8; ++dc)
#pragma unroll
            for (int r = 0; r < 4; ++r) {
                float v = O[q2][dc][r] * (q2 ? inv1[r] : inv0[r]);
                out[xb + (size_t)(q0 + q2 * 16 + quad * 4 + r) * 512 + w * 128 + dc * 16 + l16] = v;
            }
}

// ================= fp32 fallback (round 1) ==================================
__global__ __launch_bounds__(256) void xw_gemm_f32(const float* __restrict__ A,
                                                   const float* __restrict__ W,
                                                   float* __restrict__ C) {
    __shared__ float As[16][65];
    __shared__ float Bs[16][64];
    const int tid = threadIdx.x;
    const int row0 = blockIdx.y * 64, col0 = blockIdx.x * 64;
    const int ty = tid / 16, tx = tid % 16;
    float acc[4][4] = {};
    const int ar = tid / 4, ak = (tid % 4) * 4, bk = tid / 16, bn = (tid % 16) * 4;
    for (int k0 = 0; k0 < 512; k0 += 16) {
        float4 a4 = *(const float4*)(A + (size_t)(row0 + ar) * 512 + k0 + ak);
        float4 b4 = *(const float4*)(W + (size_t)(k0 + bk) * 512 + col0 + bn);
        __syncthreads();
        As[ak + 0][ar] = a4.x; As[ak + 1][ar] = a4.y;
        As[ak + 2][ar] = a4.z; As[ak + 3][ar] = a4.w;
        *(float4*)&Bs[bk][bn] = b4;
        __syncthreads();
#pragma unroll
        for (int kk = 0; kk < 16; kk++) {
            float a[4], b[4];
#pragma unroll
            for (int i = 0; i < 4; i++) a[i] = As[kk][ty * 4 + i];
#pragma unroll
            for (int j = 0; j < 4; j++) b[j] = Bs[kk][tx * 4 + j];
#pragma unroll
            for (int i = 0; i < 4; i++)
#pragma unroll
                for (int j = 0; j < 4; j++) acc[i][j] += a[i] * b[j];
        }
    }
#pragma unroll
    for (int i = 0; i < 4; i++) {
        float4 o = make_float4(acc[i][0] * INV_SCALE, acc[i][1] * INV_SCALE,
                               acc[i][2] * INV_SCALE, acc[i][3] * INV_SCALE);
        *(float4*)(C + (size_t)(row0 + ty * 4 + i) * 512 + col0 + tx * 4) = o;
    }
}

__global__ __launch_bounds__(256) void flash_f32(const float* __restrict__ x,
                                                 const float* __restrict__ qw,
                                                 float* __restrict__ out) {
    __shared__ float4 kt[16 * 136];
    const int tid = threadIdx.x;
    const int q = tid >> 3, g = tid & 7;
    const int blk = blockIdx.x;
    const int b = blk >> 6;
    const int qrow = (blk & 63) * 32 + q;
    const size_t xbase = (size_t)b * S_ * D_;
    float qwr[64];
    {
        const float4* p = (const float4*)(qw + xbase + (size_t)qrow * D_ + g * 64);
#pragma unroll
        for (int i4 = 0; i4 < 16; i4++) {
            float4 v = p[i4];
            qwr[4 * i4 + 0] = v.x; qwr[4 * i4 + 1] = v.y;
            qwr[4 * i4 + 2] = v.z; qwr[4 * i4 + 3] = v.w;
        }
    }
    float oa[64];
#pragma unroll
    for (int i = 0; i < 64; i++) oa[i] = 0.f;
    float m = -1e30f, l = 0.f;
    const float4* x4 = (const float4*)(x + xbase);
    for (int t0 = 0; t0 < S_; t0 += 16) {
        __syncthreads();
#pragma unroll
        for (int j = 0; j < 8; j++) {
            int f = tid + j * 256;
            int tt = f >> 7, c = f & 127;
            kt[tt * 136 + (c >> 4) * 17 + (c & 15)] = x4[(size_t)(t0 + tt) * 128 + c];
        }
        __syncthreads();
#pragma unroll 1
        for (int tt = 0; tt < 16; tt++) {
            float4 kv[16];
            const float4* kp = &kt[tt * 136 + g * 17];
#pragma unroll
            for (int i4 = 0; i4 < 16; i4++) kv[i4] = kp[i4];
            float s = 0.f;
#pragma unroll
            for (int i4 = 0; i4 < 16; i4++)
                s += qwr[4 * i4] * kv[i4].x + qwr[4 * i4 + 1] * kv[i4].y
                   + qwr[4 * i4 + 2] * kv[i4].z + qwr[4 * i4 + 3] * kv[i4].w;
            s += __shfl_xor(s, 1, 64); s += __shfl_xor(s, 2, 64); s += __shfl_xor(s, 4, 64);
            if (s > m) {
                float alpha = __expf(m - s);
                l *= alpha;
#pragma unroll
                for (int i = 0; i < 64; i++) oa[i] *= alpha;
                m = s;
            }
            float p = __expf(s - m);
            l += p;
#pragma unroll
            for (int i4 = 0; i4 < 16; i4++) {
                oa[4 * i4 + 0] += p * kv[i4].x; oa[4 * i4 + 1] += p * kv[i4].y;
                oa[4 * i4 + 2] += p * kv[i4].z; oa[4 * i4 + 3] += p * kv[i4].w;
            }
        }
    }
    float inv_l = 1.0f / l;
    float4* op = (float4*)(out + xbase + (size_t)qrow * D_ + g * 64);
#pragma unroll
    for (int i4 = 0; i4 < 16; i4++)
        op[i4] = make_float4(oa[4 * i4] * inv_l, oa[4 * i4 + 1] * inv_l,
                             oa[4 * i4 + 2] * inv_l, oa[4 * i4 + 3] * inv_l);
}

// ================= launch ====================================================
extern "C" void kernel_launch(void* const* d_in, const int* in_sizes, int n_in,
                              void* d_out, int out_size, void* d_ws, size_t ws_size,
                              hipStream_t stream) {
    const float* x = (const float*)d_in[0];
    const float* W = (const float*)d_in[1];
    float* out = (float*)d_out;

    const size_t F16 = (size_t)HSZ * sizeof(_Float16);     // 16,777,216
    const size_t off_qwh = 0;
    const size_t off_xh  = F16;
    const size_t off_xhT = 2 * F16;
    const size_t off_WhT = 3 * F16;
    const size_t base    = 3 * F16 + 512 * 512 * sizeof(_Float16);   // 50,855,936

    if (ws_size >= base) {
        _Float16* qwh = (_Float16*)((char*)d_ws + off_qwh);
        _Float16* xh  = (_Float16*)((char*)d_ws + off_xh);
        _Float16* xhT = (_Float16*)((char*)d_ws + off_xhT);
        _Float16* WhT = (_Float16*)((char*)d_ws + off_WhT);

        cvt_all<<<2112, 256, 0, stream>>>(x, W, xh, xhT, WhT);
        gemm_h<<<512, 256, 0, stream>>>(xh, WhT, qwh);
        flash5<<<512, 256, 0, stream>>>(xh, xhT, qwh, out);
    } else {
        const size_t needf = (size_t)HSZ * sizeof(float);
        float* xw = (ws_size >= needf) ? (float*)d_ws : out;
        dim3 g1(512 / 64, (B_ * S_) / 64);
        xw_gemm_f32<<<g1, 256, 0, stream>>>(x, W, xw);
        flash_f32<<<B_ * (S_ / 32), 256, 0, stream>>>(x, xw, out);
    }
}